// Round 3
// baseline (509.576 us; speedup 1.0000x reference)
//
#include <hip/hip_runtime.h>
#include <hip/hip_bf16.h>
#include <stdint.h>

#define IN_F   4096
#define OUT_F  4096
#define BATCH  8192
#define CAP    492

typedef __bf16 v8bf __attribute__((ext_vector_type(8)));
typedef float  v4f  __attribute__((ext_vector_type(4)));

// ---------------------------------------------------------------------------
// Convert fp32 X -> bf16 Xb (row-major, same layout). 8 elements/thread.
// ---------------------------------------------------------------------------
__global__ __launch_bounds__(256) void convert_x_kernel(
    const float* __restrict__ X, v8bf* __restrict__ Xb)
{
    const size_t i = (size_t)blockIdx.x * 256 + threadIdx.x;
    const float* p = X + i * 8;
    v8bf o;
    #pragma unroll
    for (int j = 0; j < 8; ++j) o[j] = (__bf16)p[j];   // RN conversion
    Xb[i] = o;
}

// ---------------------------------------------------------------------------
// Densify: W[o, i] bf16 row-major [OUT_F x IN_F] from padded CSR (fp32 vals).
// Must ACCUMULATE duplicates (random col_idx repeats within a row).
// One block = 2 rows, fp32 accumulation in LDS, bf16x2 packed write-out.
// ---------------------------------------------------------------------------
__global__ __launch_bounds__(256) void densify_kernel(
    const float* __restrict__ values,
    const int* __restrict__ col_idx,
    __hip_bfloat16* __restrict__ W)
{
    __shared__ float rowf[2 * IN_F];          // 32 KiB
    const int t = threadIdx.x;

    #pragma unroll
    for (int i = 0; i < (2 * IN_F) / 256; ++i)
        rowf[t + i * 256] = 0.0f;
    __syncthreads();

    const int r    = t >> 7;                  // 0..1 local row
    const int j    = t & 127;                 // 128 threads per row
    const int o    = blockIdx.x * 2 + r;
    const int base = o * CAP;
    for (int k = j; k < CAP; k += 128) {
        float v = values[base + k];           // padding slots are 0
        int   c = col_idx[base + k];
        atomicAdd(&rowf[r * IN_F + c], v);
    }
    __syncthreads();

    __hip_bfloat162* W2 = reinterpret_cast<__hip_bfloat162*>(W) + (size_t)blockIdx.x * IN_F;
    #pragma unroll
    for (int i = 0; i < IN_F / 256; ++i) {
        int idx = t + i * 256;
        __hip_bfloat162 h2;
        h2.x = __float2bfloat16(rowf[2 * idx]);
        h2.y = __float2bfloat16(rowf[2 * idx + 1]);
        W2[idx] = h2;
    }
}

// ---------------------------------------------------------------------------
// GEMM + bias: Y[b, o] = Xb[b, :] . W[o, :] + bias[o]   (fp32 out)
// 128x128 tile, BK=64, plain uint4 staging (m93 recipe), 16x16x32 bf16 MFMA.
// LDS layout: slot(m, j) holds 16B k-granule (m, j ^ (m&7)); fragment reads
// use ko = (j*4+q) ^ (ml&7) -> conflict-light ds_read_b128.
// ---------------------------------------------------------------------------
__global__ __launch_bounds__(256) void gemm_bias_kernel(
    const __hip_bfloat16* __restrict__ X,     // [BATCH, IN_F] bf16
    const __hip_bfloat16* __restrict__ W,     // [OUT_F, IN_F] bf16
    const float* __restrict__ bias,           // [OUT_F] fp32
    float* __restrict__ Y)                    // [BATCH, OUT_F] fp32
{
    __shared__ uint4 smem[2048];              // 32 KiB: A [0,1024), B [1024,2048)

    const int t    = threadIdx.x;
    const int wave = t >> 6;
    const int lane = t & 63;
    const int ml   = lane & 15;               // m (A) / n (B) / col (C) within 16-frag
    const int q    = lane >> 4;               // quad
    const int wm   = wave >> 1;               // wave tile 2x2
    const int wn   = wave & 1;
    const int bm   = blockIdx.y;              // batch tiles (64)
    const int bn   = blockIdx.x;              // output tiles (32)

    // staging: thread t, chunk c -> slot s = c*256 + t
    //   m(s) = c*32 + (t>>3), slot k8 = t&7; fetch global granule (t&7)^(m&7)
    const int trow = t >> 3;                  // 0..31
    const int k8s  = (t & 7) ^ (trow & 7);
    const __hip_bfloat16* gA = X + (size_t)(bm * 128 + trow) * IN_F + k8s * 8;
    const __hip_bfloat16* gB = W + (size_t)(bn * 128 + trow) * IN_F + k8s * 8;

    const int xr = ml & 7;
    int aBase[4], bBase[4];
    #pragma unroll
    for (int mb = 0; mb < 4; ++mb) aBase[mb] = (wm * 64 + mb * 16 + ml) * 8;
    #pragma unroll
    for (int nf = 0; nf < 4; ++nf) bBase[nf] = 1024 + (wn * 64 + nf * 16 + ml) * 8;

    v4f acc[4][4] = {};

    for (int kt = 0; kt < IN_F / 64; ++kt) {
        uint4 ra[4], rb[4];
        #pragma unroll
        for (int c = 0; c < 4; ++c) {
            ra[c] = *reinterpret_cast<const uint4*>(gA + (size_t)kt * 64 + (size_t)c * 32 * IN_F);
            rb[c] = *reinterpret_cast<const uint4*>(gB + (size_t)kt * 64 + (size_t)c * 32 * IN_F);
        }
        #pragma unroll
        for (int c = 0; c < 4; ++c) {
            smem[c * 256 + t]        = ra[c];
            smem[1024 + c * 256 + t] = rb[c];
        }
        __syncthreads();

        #pragma unroll
        for (int j = 0; j < 2; ++j) {
            const int ko = (j * 4 + q) ^ xr;
            v8bf a[4], b[4];
            #pragma unroll
            for (int mb = 0; mb < 4; ++mb)
                a[mb] = *reinterpret_cast<const v8bf*>(&smem[aBase[mb] + ko]);
            #pragma unroll
            for (int nf = 0; nf < 4; ++nf)
                b[nf] = *reinterpret_cast<const v8bf*>(&smem[bBase[nf] + ko]);
            #pragma unroll
            for (int mb = 0; mb < 4; ++mb)
                #pragma unroll
                for (int nf = 0; nf < 4; ++nf)
                    acc[mb][nf] = __builtin_amdgcn_mfma_f32_16x16x32_bf16(
                        a[mb], b[nf], acc[mb][nf], 0, 0, 0);
        }
        __syncthreads();
    }

    // epilogue: C/D layout (m89/m91): col = lane&15, row = q*4 + reg
    float bf[4];
    #pragma unroll
    for (int nf = 0; nf < 4; ++nf)
        bf[nf] = bias[bn * 128 + wn * 64 + nf * 16 + ml];

    #pragma unroll
    for (int mb = 0; mb < 4; ++mb) {
        const int row0 = bm * 128 + wm * 64 + mb * 16 + q * 4;
        #pragma unroll
        for (int nf = 0; nf < 4; ++nf) {
            const int col = bn * 128 + wn * 64 + nf * 16 + ml;
            float* yp = Y + (size_t)row0 * OUT_F + col;
            #pragma unroll
            for (int r = 0; r < 4; ++r)
                yp[(size_t)r * OUT_F] = acc[mb][nf][r] + bf[nf];
        }
    }
}

// ---------------------------------------------------------------------------
// Fallback (ws too small): fp32 LDS-staged gather.
// ---------------------------------------------------------------------------
__global__ __launch_bounds__(256) void fallback_kernel(
    const float* __restrict__ x,
    const float* __restrict__ values,
    const int* __restrict__ col_idx,
    const float* __restrict__ bias,
    float* __restrict__ y)
{
    __shared__ float xrow[IN_F];
    const int b = blockIdx.y;
    const int t = threadIdx.x;
    for (int i = t; i < IN_F; i += 256)
        xrow[i] = x[(size_t)b * IN_F + i];
    __syncthreads();
    const int o    = blockIdx.x * 256 + t;
    const int base = o * CAP;
    float acc = bias[o];
    for (int k = 0; k < CAP; ++k)
        acc += values[base + k] * xrow[col_idx[base + k]];
    y[(size_t)b * OUT_F + o] = acc;
}

extern "C" void kernel_launch(void* const* d_in, const int* in_sizes, int n_in,
                              void* d_out, int out_size, void* d_ws, size_t ws_size,
                              hipStream_t stream)
{
    const float* x      = (const float*)d_in[0];
    const float* values = (const float*)d_in[1];
    const int*   colidx = (const int*)d_in[2];
    const float* bias   = (const float*)d_in[3];
    float*       y      = (float*)d_out;

    const size_t w_bytes  = (size_t)OUT_F * IN_F * sizeof(__hip_bfloat16);  // 32 MiB
    const size_t xb_bytes = (size_t)BATCH * IN_F * sizeof(__hip_bfloat16);  // 64 MiB
    if (ws_size >= w_bytes + xb_bytes) {
        __hip_bfloat16* W  = (__hip_bfloat16*)d_ws;
        __hip_bfloat16* Xb = (__hip_bfloat16*)((char*)d_ws + w_bytes);

        convert_x_kernel<<<(BATCH * IN_F) / (256 * 8), 256, 0, stream>>>(x, (v8bf*)Xb);
        densify_kernel<<<OUT_F / 2, 256, 0, stream>>>(values, colidx, W);
        dim3 grid(OUT_F / 128, BATCH / 128);
        gemm_bias_kernel<<<grid, 256, 0, stream>>>(Xb, W, bias, y);
    } else {
        dim3 grid(OUT_F / 256, BATCH);
        fallback_kernel<<<grid, 256, 0, stream>>>(x, values, colidx, bias, y);
    }
}

// Round 4
// 475.209 us; speedup vs baseline: 1.0723x; 1.0723x over previous
//
#include <hip/hip_runtime.h>
#include <hip/hip_bf16.h>
#include <stdint.h>

#define IN_F   4096
#define OUT_F  4096
#define BATCH  8192
#define CAP    492

typedef __bf16 v8bf __attribute__((ext_vector_type(8)));
typedef __bf16 v4bf __attribute__((ext_vector_type(4)));
typedef float  v4f  __attribute__((ext_vector_type(4)));

// proper addrspace casts (addrspacecast, NOT integer truncation)
#define GPTR(p) ((const __attribute__((address_space(1))) void*)(p))
#define LPTR(p) ((__attribute__((address_space(3))) void*)(p))

#define CONV_BLOCKS ((BATCH * IN_F / 4) / 256)   // 32768: one float4 per thread
#define DENS_BLOCKS (OUT_F / 2)                  // 2048: two rows per block

// ---------------------------------------------------------------------------
// prep: fused X-convert (fp32 -> bf16, fully coalesced 16B-in/8B-out) and
// densify (padded CSR -> dense bf16 W[OUT_F x IN_F], fp32 LDS accumulation
// for duplicate columns).
// ---------------------------------------------------------------------------
__global__ __launch_bounds__(256) void prep_kernel(
    const float* __restrict__ X,        // [BATCH, IN_F] fp32
    v4bf* __restrict__ Xb,              // [BATCH*IN_F/4] bf16x4 out
    const float* __restrict__ values,   // [OUT_F, CAP] fp32
    const int* __restrict__ col_idx,    // [OUT_F, CAP]
    __hip_bfloat16* __restrict__ W)     // [OUT_F, IN_F] bf16 out
{
    __shared__ float rowf[2 * IN_F];    // used by densify blocks only (32 KiB)
    const int t = threadIdx.x;

    if (blockIdx.x < CONV_BLOCKS) {
        // ---- convert part: thread reads one float4, writes one bf16x4 ----
        const size_t i = (size_t)blockIdx.x * 256 + t;
        const float4 f = reinterpret_cast<const float4*>(X)[i];
        v4bf o;
        o[0] = (__bf16)f.x; o[1] = (__bf16)f.y;
        o[2] = (__bf16)f.z; o[3] = (__bf16)f.w;
        Xb[i] = o;
        return;
    }

    // ---- densify part: 2 output rows per block ----
    const int bid = blockIdx.x - CONV_BLOCKS;

    #pragma unroll
    for (int i = 0; i < (2 * IN_F) / 256; ++i)
        rowf[t + i * 256] = 0.0f;
    __syncthreads();

    const int r    = t >> 7;                  // 0..1 local row
    const int j    = t & 127;                 // 128 threads per row
    const int o    = bid * 2 + r;
    const int base = o * CAP;
    for (int k = j; k < CAP; k += 128) {
        float v = values[base + k];           // padding slots are exactly 0
        int   c = col_idx[base + k];
        atomicAdd(&rowf[r * IN_F + c], v);    // duplicates must accumulate
    }
    __syncthreads();

    __hip_bfloat162* W2 = reinterpret_cast<__hip_bfloat162*>(W) + (size_t)bid * IN_F;
    #pragma unroll
    for (int i = 0; i < IN_F / 256; ++i) {
        int idx = t + i * 256;
        __hip_bfloat162 h2;
        h2.x = __float2bfloat16(rowf[2 * idx]);
        h2.y = __float2bfloat16(rowf[2 * idx + 1]);
        W2[idx] = h2;
    }
}

// ---------------------------------------------------------------------------
// GEMM + bias: Y[b, o] = Xb[b, :] . W[o, :] + bias[o]   (fp32 out)
// m97 recipe: 128x128 tile, BK=64, global_load_lds width=16 staging,
// mfma_f32_16x16x32_bf16, 4 waves x (64x64 = 4x4 16x16 frags).
// LDS layout: slot(m, j) holds 16B k-granule (m, j ^ (m&7)); fragment reads
// use ko = (j*4+q) ^ (ml&7) -> conflict-free ds_read_b128 (round-3: 0 confl).
// ---------------------------------------------------------------------------
__global__ __launch_bounds__(256) void gemm_bias_kernel(
    const __hip_bfloat16* __restrict__ X,     // [BATCH, IN_F] bf16
    const __hip_bfloat16* __restrict__ W,     // [OUT_F, IN_F] bf16
    const float* __restrict__ bias,           // [OUT_F] fp32
    float* __restrict__ Y)                    // [BATCH, OUT_F] fp32
{
    __shared__ uint4 smem[2048];              // 32 KiB: A [0,1024), B [1024,2048)

    const int t    = threadIdx.x;
    const int wave = t >> 6;
    const int lane = t & 63;
    const int ml   = lane & 15;               // m (A) / n (B) / col (C) within 16-frag
    const int q    = lane >> 4;               // quad
    const int wm   = wave >> 1;               // wave tile 2x2
    const int wn   = wave & 1;
    const int bm   = blockIdx.y;              // batch tiles (64)
    const int bn   = blockIdx.x;              // output tiles (32)

    // staging: wave w lane l, chunk c -> LDS slot c*256 + w*64 + l  (= c*256+t)
    //   m(slot) = c*32 + (t>>3), slot k8 = t&7; fetch global granule (t&7)^(m&7)
    const int trow = t >> 3;                  // 0..31
    const int k8s  = (t & 7) ^ (trow & 7);    // c*32 doesn't change m&7
    const __hip_bfloat16* gA = X + (size_t)(bm * 128 + trow) * IN_F + k8s * 8;
    const __hip_bfloat16* gB = W + (size_t)(bn * 128 + trow) * IN_F + k8s * 8;

    const int xr = ml & 7;
    int aBase[4], bBase[4];
    #pragma unroll
    for (int mb = 0; mb < 4; ++mb) aBase[mb] = (wm * 64 + mb * 16 + ml) * 8;
    #pragma unroll
    for (int nf = 0; nf < 4; ++nf) bBase[nf] = 1024 + (wn * 64 + nf * 16 + ml) * 8;

    v4f acc[4][4] = {};

    for (int kt = 0; kt < IN_F / 64; ++kt) {
        const __hip_bfloat16* pa = gA + kt * 64;
        const __hip_bfloat16* pb = gB + kt * 64;
        #pragma unroll
        for (int c = 0; c < 4; ++c)
            __builtin_amdgcn_global_load_lds(GPTR(pa + (size_t)c * 32 * IN_F),
                                             LPTR(&smem[c * 256 + wave * 64]), 16, 0, 0);
        #pragma unroll
        for (int c = 0; c < 4; ++c)
            __builtin_amdgcn_global_load_lds(GPTR(pb + (size_t)c * 32 * IN_F),
                                             LPTR(&smem[1024 + c * 256 + wave * 64]), 16, 0, 0);
        __syncthreads();   // compiler emits vmcnt(0) drain before s_barrier

        #pragma unroll
        for (int j = 0; j < 2; ++j) {
            const int ko = (j * 4 + q) ^ xr;
            v8bf a[4], b[4];
            #pragma unroll
            for (int mb = 0; mb < 4; ++mb)
                a[mb] = *reinterpret_cast<const v8bf*>(&smem[aBase[mb] + ko]);
            #pragma unroll
            for (int nf = 0; nf < 4; ++nf)
                b[nf] = *reinterpret_cast<const v8bf*>(&smem[bBase[nf] + ko]);
            #pragma unroll
            for (int mb = 0; mb < 4; ++mb)
                #pragma unroll
                for (int nf = 0; nf < 4; ++nf)
                    acc[mb][nf] = __builtin_amdgcn_mfma_f32_16x16x32_bf16(
                        a[mb], b[nf], acc[mb][nf], 0, 0, 0);
        }
        __syncthreads();
    }

    // epilogue: C/D layout (m89/m91): col = lane&15, row = q*4 + reg
    float bf[4];
    #pragma unroll
    for (int nf = 0; nf < 4; ++nf)
        bf[nf] = bias[bn * 128 + wn * 64 + nf * 16 + ml];

    #pragma unroll
    for (int mb = 0; mb < 4; ++mb) {
        const int row0 = bm * 128 + wm * 64 + mb * 16 + q * 4;
        #pragma unroll
        for (int nf = 0; nf < 4; ++nf) {
            const int col = bn * 128 + wn * 64 + nf * 16 + ml;
            float* yp = Y + (size_t)row0 * OUT_F + col;
            #pragma unroll
            for (int r = 0; r < 4; ++r)
                yp[(size_t)r * OUT_F] = acc[mb][nf][r] + bf[nf];
        }
    }
}

// ---------------------------------------------------------------------------
// Fallback (ws too small for 96 MiB): fp32 LDS-staged gather.
// ---------------------------------------------------------------------------
__global__ __launch_bounds__(256) void fallback_kernel(
    const float* __restrict__ x,
    const float* __restrict__ values,
    const int* __restrict__ col_idx,
    const float* __restrict__ bias,
    float* __restrict__ y)
{
    __shared__ float xrow[IN_F];
    const int b = blockIdx.y;
    const int t = threadIdx.x;
    for (int i = t; i < IN_F; i += 256)
        xrow[i] = x[(size_t)b * IN_F + i];
    __syncthreads();
    const int o    = blockIdx.x * 256 + t;
    const int base = o * CAP;
    float acc = bias[o];
    for (int k = 0; k < CAP; ++k)
        acc += values[base + k] * xrow[col_idx[base + k]];
    y[(size_t)b * OUT_F + o] = acc;
}

extern "C" void kernel_launch(void* const* d_in, const int* in_sizes, int n_in,
                              void* d_out, int out_size, void* d_ws, size_t ws_size,
                              hipStream_t stream)
{
    const float* x      = (const float*)d_in[0];
    const float* values = (const float*)d_in[1];
    const int*   colidx = (const int*)d_in[2];
    const float* bias   = (const float*)d_in[3];
    float*       y      = (float*)d_out;

    const size_t w_bytes  = (size_t)OUT_F * IN_F * sizeof(__hip_bfloat16);  // 32 MiB
    const size_t xb_bytes = (size_t)BATCH * IN_F * sizeof(__hip_bfloat16);  // 64 MiB
    if (ws_size >= w_bytes + xb_bytes) {
        __hip_bfloat16* W  = (__hip_bfloat16*)d_ws;
        __hip_bfloat16* Xb = (__hip_bfloat16*)((char*)d_ws + w_bytes);

        prep_kernel<<<CONV_BLOCKS + DENS_BLOCKS, 256, 0, stream>>>(
            x, (v4bf*)Xb, values, colidx, W);
        dim3 grid(OUT_F / 128, BATCH / 128);
        gemm_bias_kernel<<<grid, 256, 0, stream>>>(Xb, W, bias, y);
    } else {
        dim3 grid(OUT_F / 256, BATCH);
        fallback_kernel<<<grid, 256, 0, stream>>>(x, values, colidx, bias, y);
    }
}